// Round 7
// baseline (90.977 us; speedup 1.0000x reference)
//
#include <hip/hip_runtime.h>

typedef __attribute__((ext_vector_type(8))) __bf16 bf16x8;
typedef __attribute__((ext_vector_type(4))) float f32x4;
typedef _Float16 hf2 __attribute__((ext_vector_type(2)));
typedef _Float16 hf8 __attribute__((ext_vector_type(8)));
typedef unsigned short u16;
typedef struct { hf2 v[4]; } hf2x4;   // register-friendly view of hf8

__device__ __forceinline__ float bf2f(u16 h) {
    return __uint_as_float(((unsigned int)h) << 16);
}
__device__ __forceinline__ u16 f2bf(float f) {
    unsigned int u = __float_as_uint(f);
    u += 0x7fffu + ((u >> 16) & 1u);   // RNE
    return (u16)(u >> 16);
}

#if __has_builtin(__builtin_amdgcn_fdot2)
__device__ __forceinline__ float FDOT2(hf2 a, hf2 b, float c) {
    return __builtin_amdgcn_fdot2(a, b, c, false);
}
#else
__device__ __forceinline__ float FDOT2(hf2 a, hf2 b, float c) {
    return c + (float)a[0] + (float)a[1];   // b is all-ones in our use
}
#endif

#define GLOAD_LDS16(gsrc, ldst)                                                          \
    __builtin_amdgcn_global_load_lds(                                                    \
        (__attribute__((address_space(1))) unsigned int*)(gsrc),                         \
        (__attribute__((address_space(3))) unsigned int*)(ldst), 16, 0, 0)

// ---------------------------------------------------------------------------
// Fused f32 -> bf16/f16 convert with zero-padding to (Npad, Kpad)
// ---------------------------------------------------------------------------
struct CvtDesc { const float* src; u16* dst; int N, K, Npad, Kpad, blk0, fmt; };
struct CvtTab { CvtDesc t[11]; };

__global__ __launch_bounds__(256) void cvt_all(CvtTab tab) {
    int b = blockIdx.x;
    int ti = 0;
#pragma unroll
    for (int j = 1; j < 11; ++j)
        if (b >= tab.t[j].blk0) ti = j;
    const CvtDesc c = tab.t[ti];
    long i = (long)(b - c.blk0) * 256 + threadIdx.x;
    long tot = (long)c.Npad * c.Kpad;
    if (i >= tot) return;
    int n = (int)(i / c.Kpad);
    int k = (int)(i - (long)n * c.Kpad);
    float v = (n < c.N && k < c.K) ? c.src[(long)n * c.K + k] : 0.f;
    if (c.fmt) {
        _Float16 h = (_Float16)v;
        c.dst[i] = __builtin_bit_cast(u16, h);
    } else {
        c.dst[i] = f2bf(v);
    }
}

// ---------------------------------------------------------------------------
// bf16 MFMA GEMM body: out[m][n] = epi( sum_k A[m][k]*W[n][k] + bias[n] )
// BM=BN=BK=64, 256 threads (4 waves as 2x2), 16x16x32 MFMA.
// LDS tiles [64][64] bf16, XOR-swizzled granules via pre-swizzled global
// source + linear global_load_lds dest (rule 21).
// MODE: 0 = bf16 out to outB; 2 = f16 out to outH (stride 768).
// HASRES adds bf2f(res) after optional relu.
// ---------------------------------------------------------------------------
template<int RELU, int HASRES, int MODE>
__device__ __forceinline__ void gemm_body(
    char* lds,
    const u16* __restrict__ A, int lda,
    const u16* __restrict__ W, int ldw,
    const float* __restrict__ bias, int Nreal,
    u16* __restrict__ outB, int ldo,
    const u16* __restrict__ res,
    _Float16* __restrict__ outH,
    int nk, int mb, int nb)
{
    char* ldsA = lds;
    char* ldsB = lds + 8192;

    const int tid  = threadIdx.x;
    const int wave = tid >> 6;
    const int lane = tid & 63;
    const int wr = wave >> 1, wc = wave & 1;
    const int lr = lane & 15, lk = lane >> 4;

    f32x4 acc[2][2];
#pragma unroll
    for (int i = 0; i < 2; ++i)
#pragma unroll
        for (int j = 0; j < 2; ++j)
#pragma unroll
            for (int e = 0; e < 4; ++e) acc[i][j][e] = 0.f;

    // staging granule geometry (8KB tile = 512 granules of 16B; 2 per thread)
    const int g0 = wave * 64 + lane;
    const int r0 = g0 >> 3, l0 = (g0 & 7) ^ (r0 & 7);
    const int g1 = g0 + 256;
    const int r1 = g1 >> 3, l1 = (g1 & 7) ^ (r1 & 7);

    for (int kt = 0; kt < nk; ++kt) {
        const int kk = kt * 64;
        GLOAD_LDS16(A + (size_t)(mb + r0) * lda + kk + l0 * 8, ldsA + wave * 1024);
        GLOAD_LDS16(A + (size_t)(mb + r1) * lda + kk + l1 * 8, ldsA + 4096 + wave * 1024);
        GLOAD_LDS16(W + (size_t)(nb + r0) * ldw + kk + l0 * 8, ldsB + wave * 1024);
        GLOAD_LDS16(W + (size_t)(nb + r1) * ldw + kk + l1 * 8, ldsB + 4096 + wave * 1024);
        __syncthreads();   // compiler drains vmcnt(0) before barrier
#pragma unroll
        for (int ks = 0; ks < 2; ++ks) {
            bf16x8 af[2], bfr[2];
#pragma unroll
            for (int mi = 0; mi < 2; ++mi) {
                int m_loc = wr * 32 + mi * 16 + lr;
                int gr = (ks * 4 + lk) ^ (m_loc & 7);
                af[mi] = *(const bf16x8*)(ldsA + m_loc * 128 + gr * 16);
            }
#pragma unroll
            for (int ni = 0; ni < 2; ++ni) {
                int n_loc = wc * 32 + ni * 16 + lr;
                int gr = (ks * 4 + lk) ^ (n_loc & 7);
                bfr[ni] = *(const bf16x8*)(ldsB + n_loc * 128 + gr * 16);
            }
#pragma unroll
            for (int mi = 0; mi < 2; ++mi)
#pragma unroll
                for (int ni = 0; ni < 2; ++ni)
                    acc[mi][ni] = __builtin_amdgcn_mfma_f32_16x16x32_bf16(
                        af[mi], bfr[ni], acc[mi][ni], 0, 0, 0);
        }
        __syncthreads();
    }

    // epilogue: C/D layout col = lane&15, row = (lane>>4)*4 + reg (m89-verified)
#pragma unroll
    for (int mi = 0; mi < 2; ++mi) {
#pragma unroll
        for (int ni = 0; ni < 2; ++ni) {
            const int n_g = nb + wc * 32 + ni * 16 + lr;
            const float bv = (n_g < Nreal) ? bias[n_g] : 0.f;
#pragma unroll
            for (int r = 0; r < 4; ++r) {
                const int m_g = mb + wr * 32 + mi * 16 + lk * 4 + r;
                float v = acc[mi][ni][r] + bv;
                if (RELU) v = fmaxf(v, 0.f);
                if (HASRES) v += bf2f(res[(size_t)m_g * ldo + n_g]);
                if (MODE == 2) {
                    outH[(size_t)m_g * 768 + n_g] = (_Float16)v;
                } else {
                    outB[(size_t)m_g * ldo + n_g] = f2bf(v);
                }
            }
        }
    }
}

// merged adapter (f16 out: adFH = f16(x@aW.T + ab + xb)) and down0: share A=xb
__global__ __launch_bounds__(256) void gemm_ad0(
    const u16* __restrict__ xb,
    const u16* __restrict__ aWb, const float* __restrict__ ab,
    _Float16* __restrict__ adFH,
    const u16* __restrict__ Wd0b, const float* __restrict__ bd0,
    u16* __restrict__ h1)
{
    __shared__ __align__(16) char lds[16384];
    if (blockIdx.y < 12) {
        // adapter: no relu, residual add of xb (bf16), f16 output
        gemm_body<0, 1, 2>(lds, xb, 768, aWb, 768, ab, 768, nullptr, 768,
                           xb, adFH, 12, blockIdx.x * 64, blockIdx.y * 64);
    } else {
        gemm_body<1, 0, 0>(lds, xb, 768, Wd0b, 768, bd0, 384, h1, 384,
                           nullptr, nullptr, 12,
                           blockIdx.x * 64, (blockIdx.y - 12) * 64);
    }
}

// ---------------------------------------------------------------------------
// Fused chain: d1 -> d2 -> d3 -> u0(+h3) -> u1(+h2) -> u2 -> u3(+adF) -> featH
// Grid 128 blocks x 16 rows, 256 thr (4 waves). All activations in LDS;
// weights read direct from global (L2-resident) as MFMA B-fragments.
// Fragment layouts identical to gemm_body (A: lane(lr,lk) -> A[lr][lk*8..];
// C/D: col=lr, row=lk*4+r).
// ---------------------------------------------------------------------------
template<int K, int NPAD, int NREAL, int RES>
__device__ __forceinline__ void layer16(
    const u16* __restrict__ W, int ldw, const float* __restrict__ bias,
    const u16* actIn, int ldin,
    u16* actOut, int ldout,
    const u16* resid, int ldres)
{
    constexpr int TPW = NPAD / 64;     // 16-wide N-tiles per wave (4 waves)
    const int tid = threadIdx.x;
    const int wave = tid >> 6, lane = tid & 63;
    const int lr = lane & 15, lk = lane >> 4;

    f32x4 acc[TPW];
#pragma unroll
    for (int t = 0; t < TPW; ++t)
#pragma unroll
        for (int e = 0; e < 4; ++e) acc[t][e] = 0.f;

#pragma unroll
    for (int kk = 0; kk < K / 32; ++kk) {
        const bf16x8 a = *(const bf16x8*)&actIn[lr * ldin + kk * 32 + lk * 8];
#pragma unroll
        for (int t = 0; t < TPW; ++t) {
            const int nc = (wave * TPW + t) * 16 + lr;
            const bf16x8 b = *(const bf16x8*)&W[(size_t)nc * ldw + kk * 32 + lk * 8];
            acc[t] = __builtin_amdgcn_mfma_f32_16x16x32_bf16(a, b, acc[t], 0, 0, 0);
        }
    }
#pragma unroll
    for (int t = 0; t < TPW; ++t) {
        const int nc = (wave * TPW + t) * 16 + lr;
        const float bv = (nc < NREAL) ? bias[nc] : 0.f;
#pragma unroll
        for (int r = 0; r < 4; ++r) {
            const int row = lk * 4 + r;
            float v = fmaxf(acc[t][r] + bv, 0.f);
            if (RES) v += bf2f(resid[row * ldres + nc]);
            actOut[row * ldout + nc] = f2bf(v);
        }
    }
}

__global__ __launch_bounds__(256) void chain_full(
    const u16* __restrict__ h1,
    const u16* __restrict__ Wd1b, const float* __restrict__ bd1,
    const u16* __restrict__ Wd2b, const float* __restrict__ bd2,
    const u16* __restrict__ Wd3b, const float* __restrict__ bd3,
    const u16* __restrict__ Wu0b, const float* __restrict__ bu0,
    const u16* __restrict__ Wu1b, const float* __restrict__ bu1,
    const u16* __restrict__ Wu2b, const float* __restrict__ bu2,
    const u16* __restrict__ Wu3b, const float* __restrict__ bu3,
    const _Float16* __restrict__ adFH, _Float16* __restrict__ featH)
{
    __shared__ u16 As[16 * 392];  // h1 in; later E=[0..16*136) u0out, F u1out
    __shared__ u16 Bs[16 * 200];  // h2 skip (192w)
    __shared__ u16 Cs[16 * 136];  // h3 skip (128w, cols 96.. = 0)
    __shared__ u16 Ds[16 * 72];   // h4 (64w, cols 48.. = 0)
    __shared__ u16 Gs[16 * 392];  // u2 out (384w)
    const int tid = threadIdx.x;
    const int rb = blockIdx.x * 16;

    // stage h1: 16 rows x 48 granules of 8 bf16, coalesced b128
    for (int i = tid; i < 768; i += 256) {
        const int r = i / 48, c = i - r * 48;
        *(bf16x8*)&As[r * 392 + c * 8] =
            *(const bf16x8*)&h1[(size_t)(rb + r) * 384 + c * 8];
    }
    __syncthreads();
    layer16<384, 192, 192, 0>(Wd1b, 384, bd1, As, 392, Bs, 200, nullptr, 0);
    __syncthreads();
    layer16<192, 128,  96, 0>(Wd2b, 192, bd2, Bs, 200, Cs, 136, nullptr, 0);
    __syncthreads();
    layer16<128,  64,  48, 0>(Wd3b, 128, bd3, Cs, 136, Ds,  72, nullptr, 0);
    __syncthreads();
    u16* E = As;                 // 16 x 136
    u16* F = As + 16 * 136;      // 16 x 200
    layer16< 64, 128,  96, 1>(Wu0b,  64, bu0, Ds,  72, E, 136, Cs, 136);
    __syncthreads();
    layer16<128, 192, 192, 1>(Wu1b, 128, bu1, E, 136, F, 200, Bs, 200);
    __syncthreads();
    layer16<192, 384, 384, 0>(Wu2b, 192, bu2, F, 200, Gs, 392, nullptr, 0);
    __syncthreads();

    // u3: K=384, N=768, TPW=12; featH = f16(relu(Gs@Wu3.T + bu3) + adFH)
    {
        const int wave = tid >> 6, lane = tid & 63;
        const int lr = lane & 15, lk = lane >> 4;
        f32x4 acc[12];
#pragma unroll
        for (int t = 0; t < 12; ++t)
#pragma unroll
            for (int e = 0; e < 4; ++e) acc[t][e] = 0.f;
#pragma unroll 2
        for (int kk = 0; kk < 12; ++kk) {
            const bf16x8 a = *(const bf16x8*)&Gs[lr * 392 + kk * 32 + lk * 8];
#pragma unroll
            for (int t = 0; t < 12; ++t) {
                const int nc = (wave * 12 + t) * 16 + lr;
                const bf16x8 b =
                    *(const bf16x8*)&Wu3b[(size_t)nc * 384 + kk * 32 + lk * 8];
                acc[t] = __builtin_amdgcn_mfma_f32_16x16x32_bf16(a, b, acc[t], 0, 0, 0);
            }
        }
#pragma unroll
        for (int t = 0; t < 12; ++t) {
            const int nc = (wave * 12 + t) * 16 + lr;
            const float bv = bu3[nc];
#pragma unroll
            for (int r = 0; r < 4; ++r) {
                const int row = lk * 4 + r;
                float v = fmaxf(acc[t][r] + bv, 0.f);
                v += (float)adFH[(size_t)(rb + row) * 768 + nc];
                featH[(size_t)(rb + row) * 768 + nc] = (_Float16)v;
            }
        }
    }
}

// ---------------------------------------------------------------------------
// L1 head: part[row][z][p] = sum_{d in chunk z} -|feat[row][d] - protos[p][d]|
// (f16 in, f32 acc). Grid (16 row-blocks, 4 proto-blocks, 12 d-chunks).
// Block: 128 rows x 64 protos x 64 d. Thread: 8 rows (tr+16i) x 4 protos.
// Inner: packed-f16 sub + bitwise abs + v_dot2_f32_f16 (3 VALU per 2 d/cell).
// Non-atomic coalesced float4 stores (atomics were the R4 bottleneck).
// ---------------------------------------------------------------------------
__global__ __launch_bounds__(256) void l1_kernel(
    const _Float16* __restrict__ feat, const _Float16* __restrict__ protos,
    float* __restrict__ part)
{
    __shared__ _Float16 fs[128][64];
    __shared__ hf2 pt[32][64];        // [d-pair][proto]
    const int tid = threadIdx.x;
    const int tp = tid & 15, tr = tid >> 4;
    const int rb = blockIdx.x * 128;
    const int pb = blockIdx.y * 64;
    const int db = blockIdx.z * 64;

    // stage fs: thread -> (row r0+32k, granule g), 4 x b128, coalesced
    {
        const int g = tid & 7, r0 = tid >> 3;
#pragma unroll
        for (int k = 0; k < 4; ++k) {
            const int r = r0 + 32 * k;
            *(hf8*)&fs[r][g * 8] =
                *(const hf8*)&feat[(size_t)(rb + r) * 768 + db + g * 8];
        }
    }
    // stage pt (transposed pairs): thread owns proto sp, d-pairs q*8..q*8+7
    {
        const int sp = tid & 63, q = tid >> 6;
        const _Float16* src = &protos[(size_t)(pb + sp) * 768 + db + q * 16];
        hf8 v0 = *(const hf8*)src;
        hf8 v1 = *(const hf8*)(src + 8);
        hf2x4 w0 = __builtin_bit_cast(hf2x4, v0);
        hf2x4 w1 = __builtin_bit_cast(hf2x4, v1);
#pragma unroll
        for (int e = 0; e < 4; ++e)
            pt[q * 8 + e][sp] = w0.v[e];
#pragma unroll
        for (int e = 0; e < 4; ++e)
            pt[q * 8 + 4 + e][sp] = w1.v[e];
    }
    __syncthreads();

    float acc[8][4];
#pragma unroll
    for (int i = 0; i < 8; ++i)
#pragma unroll
        for (int j = 0; j < 4; ++j) acc[i][j] = 0.f;

    const hf2 one2 = {(_Float16)1.0f, (_Float16)1.0f};
#pragma unroll 2
    for (int g = 0; g < 8; ++g) {
        hf2x4 F2[8];
#pragma unroll
        for (int i = 0; i < 8; ++i)
            F2[i] = __builtin_bit_cast(hf2x4,
                        *(const hf8*)&fs[tr + 16 * i][g * 8]);
        hf2x4 P2[4];
#pragma unroll
        for (int q = 0; q < 4; ++q)
            P2[q] = __builtin_bit_cast(hf2x4,
                        *(const hf8*)&pt[g * 4 + q][tp * 4]);
#pragma unroll
        for (int q = 0; q < 4; ++q) {
#pragma unroll
            for (int j = 0; j < 4; ++j) {
                const hf2 pj = P2[q].v[j];
#pragma unroll
                for (int i = 0; i < 8; ++i) {
                    hf2 d = F2[i].v[q] - pj;
                    unsigned ud = __builtin_bit_cast(unsigned, d) & 0x7FFF7FFFu;
                    acc[i][j] = FDOT2(__builtin_bit_cast(hf2, ud), one2, acc[i][j]);
                }
            }
        }
    }
    // coalesced partial store: p = pb + tp*4 (mult of 4; p<200 => p+3<200)
    const int p = pb + tp * 4;
    if (p < 200) {
#pragma unroll
        for (int i = 0; i < 8; ++i) {
            float4 v = {-acc[i][0], -acc[i][1], -acc[i][2], -acc[i][3]};
            *(float4*)&part[((size_t)(rb + tr + 16 * i) * 12 + blockIdx.z) * 200 + p] = v;
        }
    }
}

// out[row][p] = sum_z part[row][z][p]; one block per row (9.6KB contiguous)
__global__ __launch_bounds__(256) void l1_reduce(
    const float* __restrict__ part, float* __restrict__ out)
{
    const int row = blockIdx.x;
    const int p = threadIdx.x;
    if (p < 200) {
        float s = 0.f;
#pragma unroll
        for (int z = 0; z < 12; ++z)
            s += part[((size_t)row * 12 + z) * 200 + p];
        out[(size_t)row * 200 + p] = s;
    }
}

// ---------------------------------------------------------------------------
// Workspace layout (bytes). Total ~23.2 MB.
// PART (19.66 MB) aliases the GEMM-era scratch (xb..adFH, dead when l1 runs).
// featH/proH live above PART.
// ---------------------------------------------------------------------------
static constexpr size_t OFF_PART  = 0;          // 2048 x 12 x 200 f32 partials
static constexpr size_t OFF_XB    = 0;          // 2048x768 bf16 (dead before l1)
static constexpr size_t OFF_AWB   = 3145728;    // 768x768 bf16
static constexpr size_t OFF_WD0   = 4325376;    // 384x768
static constexpr size_t OFF_WD1   = 4915200;    // 192x384
static constexpr size_t OFF_WD2   = 5062656;    // 128x192
static constexpr size_t OFF_WD3   = 5111808;    // 64x128
static constexpr size_t OFF_WU0   = 5128192;    // 128x64
static constexpr size_t OFF_WU1   = 5144576;    // 192x128
static constexpr size_t OFF_WU2   = 5193728;    // 384x192
static constexpr size_t OFF_WU3   = 5341184;    // 768x384
static constexpr size_t OFF_H1    = 5931008;    // 2048x384 bf16
static constexpr size_t OFF_ADF   = 11960320;   // 2048x768 f16: x + adapter(x)
static constexpr size_t OFF_FEATH = 19660800;   // 2048x768 f16: features
static constexpr size_t OFF_PROH  = 22806528;   // 256x768 f16: protos (padded)

extern "C" void kernel_launch(void* const* d_in, const int* in_sizes, int n_in,
                              void* d_out, int out_size, void* d_ws, size_t ws_size,
                              hipStream_t stream) {
    const float* x      = (const float*)d_in[0];
    const float* aW     = (const float*)d_in[1];
    const float* ab     = (const float*)d_in[2];
    const float* protos = (const float*)d_in[3];
    const float* Wd[4]  = {(const float*)d_in[4], (const float*)d_in[6],
                           (const float*)d_in[8], (const float*)d_in[10]};
    const float* bd[4]  = {(const float*)d_in[5], (const float*)d_in[7],
                           (const float*)d_in[9], (const float*)d_in[11]};
    const float* Wu[4]  = {(const float*)d_in[12], (const float*)d_in[14],
                           (const float*)d_in[16], (const float*)d_in[18]};
    const float* bu[4]  = {(const float*)d_in[13], (const float*)d_in[15],
                           (const float*)d_in[17], (const float*)d_in[19]};
    float* out = (float*)d_out;
    char* ws = (char*)d_ws;

    u16* xb    = (u16*)(ws + OFF_XB);
    u16* aWb   = (u16*)(ws + OFF_AWB);
    u16* Wd0b  = (u16*)(ws + OFF_WD0);
    u16* Wd1b  = (u16*)(ws + OFF_WD1);
    u16* Wd2b  = (u16*)(ws + OFF_WD2);
    u16* Wd3b  = (u16*)(ws + OFF_WD3);
    u16* Wu0b  = (u16*)(ws + OFF_WU0);
    u16* Wu1b  = (u16*)(ws + OFF_WU1);
    u16* Wu2b  = (u16*)(ws + OFF_WU2);
    u16* Wu3b  = (u16*)(ws + OFF_WU3);
    u16* h1    = (u16*)(ws + OFF_H1);
    float* part = (float*)(ws + OFF_PART);
    _Float16* adFH  = (_Float16*)(ws + OFF_ADF);
    _Float16* featH = (_Float16*)(ws + OFF_FEATH);
    _Float16* proH  = (_Float16*)(ws + OFF_PROH);

    // --- 1. convert/pad everything (bf16 for GEMM, f16 for L1) ---
    CvtTab tab;
    int blk = 0;
    auto set = [&](int i, const float* s, u16* d, int N, int K, int Np, int Kp,
                   int fmt) {
        tab.t[i] = {s, d, N, K, Np, Kp, blk, fmt};
        blk += (Np * Kp + 255) / 256;
    };
    set(0,  x,      xb,          2048, 768, 2048, 768, 0);
    set(1,  aW,     aWb,         768,  768, 768,  768, 0);
    set(2,  Wd[0],  Wd0b,        384,  768, 384,  768, 0);
    set(3,  Wd[1],  Wd1b,        192,  384, 192,  384, 0);
    set(4,  Wd[2],  Wd2b,        96,   192, 128,  192, 0);
    set(5,  Wd[3],  Wd3b,        48,   96,  64,   128, 0);
    set(6,  Wu[0],  Wu0b,        96,   48,  128,  64,  0);
    set(7,  Wu[1],  Wu1b,        192,  96,  192,  128, 0);
    set(8,  Wu[2],  Wu2b,        384,  192, 384,  192, 0);
    set(9,  Wu[3],  Wu3b,        768,  384, 768,  384, 0);
    set(10, protos, (u16*)proH,  200,  768, 256,  768, 1);
    cvt_all<<<blk, 256, 0, stream>>>(tab);

    // --- 2. adapter + down0 (share A=xb), then fully fused chain d1..u3 ---
    gemm_ad0<<<dim3(32, 18), 256, 0, stream>>>(xb, aWb, ab, adFH, Wd0b, bd[0], h1);
    chain_full<<<dim3(128), 256, 0, stream>>>(h1,
        Wd1b, bd[1], Wd2b, bd[2], Wd3b, bd[3],
        Wu0b, bu[0], Wu1b, bu[1], Wu2b, bu[2], Wu3b, bu[3],
        adFH, featH);

    // --- 3. L1 prototype head: partials (no atomics), then reduce ---
    l1_kernel<<<dim3(16, 4, 12), 256, 0, stream>>>(featH, proH, part);
    l1_reduce<<<dim3(2048), 256, 0, stream>>>(part, out);
}

// Round 8
// 80.562 us; speedup vs baseline: 1.1293x; 1.1293x over previous
//
#include <hip/hip_runtime.h>

typedef __attribute__((ext_vector_type(8))) __bf16 bf16x8;
typedef __attribute__((ext_vector_type(4))) float f32x4;
typedef _Float16 hf2 __attribute__((ext_vector_type(2)));
typedef _Float16 hf8 __attribute__((ext_vector_type(8)));
typedef unsigned short u16;
typedef struct { hf2 v[4]; } hf2x4;   // register-friendly view of hf8

__device__ __forceinline__ float bf2f(u16 h) {
    return __uint_as_float(((unsigned int)h) << 16);
}
__device__ __forceinline__ u16 f2bf(float f) {
    unsigned int u = __float_as_uint(f);
    u += 0x7fffu + ((u >> 16) & 1u);   // RNE
    return (u16)(u >> 16);
}

#if __has_builtin(__builtin_amdgcn_fdot2)
__device__ __forceinline__ float FDOT2(hf2 a, hf2 b, float c) {
    return __builtin_amdgcn_fdot2(a, b, c, false);
}
#else
__device__ __forceinline__ float FDOT2(hf2 a, hf2 b, float c) {
    return c + (float)a[0] + (float)a[1];   // b is all-ones in our use
}
#endif

#define GLOAD_LDS16(gsrc, ldst)                                                          \
    __builtin_amdgcn_global_load_lds(                                                    \
        (__attribute__((address_space(1))) unsigned int*)(gsrc),                         \
        (__attribute__((address_space(3))) unsigned int*)(ldst), 16, 0, 0)

// ---------------------------------------------------------------------------
// Fused f32 -> bf16/f16 convert with zero-padding to (Npad, Kpad)
// ---------------------------------------------------------------------------
struct CvtDesc { const float* src; u16* dst; int N, K, Npad, Kpad, blk0, fmt; };
struct CvtTab { CvtDesc t[11]; };

__global__ __launch_bounds__(256) void cvt_all(CvtTab tab) {
    int b = blockIdx.x;
    int ti = 0;
#pragma unroll
    for (int j = 1; j < 11; ++j)
        if (b >= tab.t[j].blk0) ti = j;
    const CvtDesc c = tab.t[ti];
    long i = (long)(b - c.blk0) * 256 + threadIdx.x;
    long tot = (long)c.Npad * c.Kpad;
    if (i >= tot) return;
    int n = (int)(i / c.Kpad);
    int k = (int)(i - (long)n * c.Kpad);
    float v = (n < c.N && k < c.K) ? c.src[(long)n * c.K + k] : 0.f;
    if (c.fmt) {
        _Float16 h = (_Float16)v;
        c.dst[i] = __builtin_bit_cast(u16, h);
    } else {
        c.dst[i] = f2bf(v);
    }
}

// ---------------------------------------------------------------------------
// 128x64-tile double-buffered bf16 MFMA GEMM (T3-minimal 2-phase pipeline):
//   STAGE(next K-tile) issued BEFORE COMPUTE(current) so the ~900-cyc load
//   latency hides under ds_read+MFMA; one vmcnt-drain barrier per K-step.
// 256 thr = 4 waves as 2x2 over (128,64); wave tile 64x32 = acc[4][2].
// LDS 2 x (16KB A + 8KB B), XOR-swizzled granules via pre-swizzled global
// source + linear global_load_lds dest (rule 21).
// Epilogue: +bias, opt relu, opt residual (bf16 or f16), out bf16 or f16.
// ---------------------------------------------------------------------------
template<int RELU, int HASRES, int RESF16, int MODE>
__device__ __forceinline__ void gemm128_body(
    char* lds,
    const u16* __restrict__ A, int lda,
    const u16* __restrict__ W, int ldw,
    const float* __restrict__ bias,
    u16* __restrict__ outB, int ldo,
    const void* __restrict__ res, int ldr,
    _Float16* __restrict__ outH,
    int nk, int mb, int nb)
{
    const int tid = threadIdx.x;
    const int wave = tid >> 6, lane = tid & 63;
    const int lr = lane & 15, lk = lane >> 4;
    const int wr = wave >> 1, wc = wave & 1;

    f32x4 acc[4][2];
#pragma unroll
    for (int i = 0; i < 4; ++i)
#pragma unroll
        for (int j = 0; j < 2; ++j)
#pragma unroll
            for (int e = 0; e < 4; ++e) acc[i][j][e] = 0.f;

    // staging geometry: A = 1024 granules (4/thread), B = 512 (2/thread)
    int ra[4], la[4], rb[2], lb[2];
#pragma unroll
    for (int t = 0; t < 4; ++t) {
        int g = t * 256 + tid;
        ra[t] = g >> 3; la[t] = (g & 7) ^ (ra[t] & 7);
    }
#pragma unroll
    for (int t = 0; t < 2; ++t) {
        int g = t * 256 + tid;
        rb[t] = g >> 3; lb[t] = (g & 7) ^ (rb[t] & 7);
    }

    auto STAGE = [&](int b, int kt) {
        const int kk = kt * 64;
        char* dA = lds + b * 24576;
        char* dB = dA + 16384;
#pragma unroll
        for (int t = 0; t < 4; ++t)
            GLOAD_LDS16(A + (size_t)(mb + ra[t]) * lda + kk + la[t] * 8,
                        dA + t * 4096 + wave * 1024);
#pragma unroll
        for (int t = 0; t < 2; ++t)
            GLOAD_LDS16(W + (size_t)(nb + rb[t]) * ldw + kk + lb[t] * 8,
                        dB + t * 4096 + wave * 1024);
    };
    auto COMPUTE = [&](int b) {
        char* sA = lds + b * 24576;
        char* sB = sA + 16384;
#pragma unroll
        for (int ks = 0; ks < 2; ++ks) {
            bf16x8 af[4], bfr[2];
#pragma unroll
            for (int mi = 0; mi < 4; ++mi) {
                int m_loc = wr * 64 + mi * 16 + lr;
                int gr = (ks * 4 + lk) ^ (m_loc & 7);
                af[mi] = *(const bf16x8*)(sA + m_loc * 128 + gr * 16);
            }
#pragma unroll
            for (int ni = 0; ni < 2; ++ni) {
                int n_loc = wc * 32 + ni * 16 + lr;
                int gr = (ks * 4 + lk) ^ (n_loc & 7);
                bfr[ni] = *(const bf16x8*)(sB + n_loc * 128 + gr * 16);
            }
#pragma unroll
            for (int mi = 0; mi < 4; ++mi)
#pragma unroll
                for (int ni = 0; ni < 2; ++ni)
                    acc[mi][ni] = __builtin_amdgcn_mfma_f32_16x16x32_bf16(
                        af[mi], bfr[ni], acc[mi][ni], 0, 0, 0);
        }
    };

    STAGE(0, 0);
    __syncthreads();
    int b = 0;
    for (int kt = 0; kt < nk - 1; ++kt) {
        STAGE(b ^ 1, kt + 1);     // prefetch next tile (stays in flight)
        COMPUTE(b);               // ds_read + MFMA on current tile
        __syncthreads();          // single vmcnt-drain point per K-step
        b ^= 1;
    }
    COMPUTE(b);

    // epilogue: C/D layout col = lane&15, row = (lane>>4)*4 + reg
#pragma unroll
    for (int mi = 0; mi < 4; ++mi) {
#pragma unroll
        for (int ni = 0; ni < 2; ++ni) {
            const int n_g = nb + wc * 32 + ni * 16 + lr;
            const float bv = bias[n_g];
#pragma unroll
            for (int r = 0; r < 4; ++r) {
                const int m_g = mb + wr * 64 + mi * 16 + lk * 4 + r;
                float v = acc[mi][ni][r] + bv;
                if (RELU) v = fmaxf(v, 0.f);
                if (HASRES) {
                    if (RESF16)
                        v += (float)((const _Float16*)res)[(size_t)m_g * ldr + n_g];
                    else
                        v += bf2f(((const u16*)res)[(size_t)m_g * ldr + n_g]);
                }
                if (MODE == 2) outH[(size_t)m_g * 768 + n_g] = (_Float16)v;
                else           outB[(size_t)m_g * ldo + n_g] = f2bf(v);
            }
        }
    }
}

// merged adapter (adFH = f16(x@aW.T + ab + xb)) and down0 (h1): share A=xb
__global__ __launch_bounds__(256) void gemm_ad0(
    const u16* __restrict__ xb,
    const u16* __restrict__ aWb, const float* __restrict__ ab,
    _Float16* __restrict__ adFH,
    const u16* __restrict__ Wd0b, const float* __restrict__ bd0,
    u16* __restrict__ h1)
{
    __shared__ __align__(16) char lds[49152];
    if (blockIdx.y < 12) {
        gemm128_body<0, 1, 0, 2>(lds, xb, 768, aWb, 768, ab, nullptr, 0,
                                 xb, 768, adFH, 12,
                                 blockIdx.x * 128, blockIdx.y * 64);
    } else {
        gemm128_body<1, 0, 0, 0>(lds, xb, 768, Wd0b, 768, bd0, h1, 384,
                                 nullptr, 0, nullptr, 12,
                                 blockIdx.x * 128, (blockIdx.y - 12) * 64);
    }
}

// u3: featH = f16(relu(u2@Wu3.T + bu3) + adFH)
__global__ __launch_bounds__(256) void gemm_u3(
    const u16* __restrict__ u2, const u16* __restrict__ Wu3b,
    const float* __restrict__ bu3, const _Float16* __restrict__ adFH,
    _Float16* __restrict__ featH)
{
    __shared__ __align__(16) char lds[49152];
    gemm128_body<1, 1, 1, 2>(lds, u2, 384, Wu3b, 384, bu3, nullptr, 0,
                             adFH, 768, featH, 6,
                             blockIdx.x * 128, blockIdx.y * 64);
}

// ---------------------------------------------------------------------------
// Fused middle chain: d1 -> d2 -> d3 -> u0(+h3) -> u1(+h2) -> u2, one launch.
// Grid 128 blocks x 16 rows, 256 thr (4 waves). Activations live in LDS;
// weights (L2-resident) read directly from global as MFMA B-fragments.
// ---------------------------------------------------------------------------
template<int K, int NPAD, int NREAL, int RES, int OUTG>
__device__ __forceinline__ void layer16(
    const u16* __restrict__ W, int ldw, const float* __restrict__ bias,
    const u16* actIn, int ldin,
    u16* actOut, int ldout,
    const u16* resid, int ldres,
    u16* __restrict__ gout, int ldg)
{
    constexpr int TPW = NPAD / 64;     // 16-wide N-tiles per wave (4 waves)
    const int tid = threadIdx.x;
    const int wave = tid >> 6, lane = tid & 63;
    const int lr = lane & 15, lk = lane >> 4;

    f32x4 acc[TPW];
#pragma unroll
    for (int t = 0; t < TPW; ++t)
#pragma unroll
        for (int e = 0; e < 4; ++e) acc[t][e] = 0.f;

#pragma unroll
    for (int kk = 0; kk < K / 32; ++kk) {
        const bf16x8 a = *(const bf16x8*)&actIn[lr * ldin + kk * 32 + lk * 8];
#pragma unroll
        for (int t = 0; t < TPW; ++t) {
            const int nc = (wave * TPW + t) * 16 + lr;
            const bf16x8 b = *(const bf16x8*)&W[(size_t)nc * ldw + kk * 32 + lk * 8];
            acc[t] = __builtin_amdgcn_mfma_f32_16x16x32_bf16(a, b, acc[t], 0, 0, 0);
        }
    }
#pragma unroll
    for (int t = 0; t < TPW; ++t) {
        const int nc = (wave * TPW + t) * 16 + lr;
        const float bv = (nc < NREAL) ? bias[nc] : 0.f;
#pragma unroll
        for (int r = 0; r < 4; ++r) {
            const int row = lk * 4 + r;
            float v = fmaxf(acc[t][r] + bv, 0.f);
            if (RES) v += bf2f(resid[row * ldres + nc]);
            const u16 o = f2bf(v);
            if (OUTG) gout[(size_t)row * ldg + nc] = o;
            else      actOut[row * ldout + nc] = o;
        }
    }
}

__global__ __launch_bounds__(256) void chain_mid(
    const u16* __restrict__ h1,
    const u16* __restrict__ Wd1b, const float* __restrict__ bd1,
    const u16* __restrict__ Wd2b, const float* __restrict__ bd2,
    const u16* __restrict__ Wd3b, const float* __restrict__ bd3,
    const u16* __restrict__ Wu0b, const float* __restrict__ bu0,
    const u16* __restrict__ Wu1b, const float* __restrict__ bu1,
    const u16* __restrict__ Wu2b, const float* __restrict__ bu2,
    u16* __restrict__ u2)
{
    __shared__ u16 As[16 * 392];  // h1 in; later E=[0..16*136) u0out, F u1out
    __shared__ u16 Bs[16 * 200];  // h2 skip (192w)
    __shared__ u16 Cs[16 * 136];  // h3 skip (128w, cols 96.. = 0)
    __shared__ u16 Ds[16 * 72];   // h4 (64w, cols 48.. = 0)
    const int tid = threadIdx.x;
    const int rb = blockIdx.x * 16;

    // stage h1: 16 rows x 48 granules of 8 bf16, coalesced b128
    for (int i = tid; i < 768; i += 256) {
        const int r = i / 48, c = i - r * 48;
        *(bf16x8*)&As[r * 392 + c * 8] =
            *(const bf16x8*)&h1[(size_t)(rb + r) * 384 + c * 8];
    }
    __syncthreads();
    layer16<384, 192, 192, 0, 0>(Wd1b, 384, bd1, As, 392, Bs, 200, nullptr, 0, nullptr, 0);
    __syncthreads();
    layer16<192, 128,  96, 0, 0>(Wd2b, 192, bd2, Bs, 200, Cs, 136, nullptr, 0, nullptr, 0);
    __syncthreads();
    layer16<128,  64,  48, 0, 0>(Wd3b, 128, bd3, Cs, 136, Ds,  72, nullptr, 0, nullptr, 0);
    __syncthreads();
    u16* E = As;                 // 16 x 136
    u16* F = As + 16 * 136;      // 16 x 200
    layer16< 64, 128,  96, 1, 0>(Wu0b,  64, bu0, Ds,  72, E, 136, Cs, 136, nullptr, 0);
    __syncthreads();
    layer16<128, 192, 192, 1, 0>(Wu1b, 128, bu1, E, 136, F, 200, Bs, 200, nullptr, 0);
    __syncthreads();
    layer16<192, 384, 384, 0, 1>(Wu2b, 192, bu2, F, 200, nullptr, 0, nullptr, 0,
                                 u2 + (size_t)rb * 384, 384);
}

// ---------------------------------------------------------------------------
// L1 head: part[row][z][p] = sum_{d in chunk z} -|feat[row][d] - protos[p][d]|
// (f16 in, f32 acc). Grid (16 row-blocks, 4 proto-blocks, 12 d-chunks).
// Block: 128 rows x 64 protos x 64 d. Thread: 8 rows (tr+16i) x 4 protos.
// Non-atomic coalesced float4 stores (atomics were the R4 bottleneck).
// ---------------------------------------------------------------------------
__global__ __launch_bounds__(256) void l1_kernel(
    const _Float16* __restrict__ feat, const _Float16* __restrict__ protos,
    float* __restrict__ part)
{
    __shared__ _Float16 fs[128][64];
    __shared__ hf2 pt[32][64];        // [d-pair][proto]
    const int tid = threadIdx.x;
    const int tp = tid & 15, tr = tid >> 4;
    const int rb = blockIdx.x * 128;
    const int pb = blockIdx.y * 64;
    const int db = blockIdx.z * 64;

    {
        const int g = tid & 7, r0 = tid >> 3;
#pragma unroll
        for (int k = 0; k < 4; ++k) {
            const int r = r0 + 32 * k;
            *(hf8*)&fs[r][g * 8] =
                *(const hf8*)&feat[(size_t)(rb + r) * 768 + db + g * 8];
        }
    }
    {
        const int sp = tid & 63, q = tid >> 6;
        const _Float16* src = &protos[(size_t)(pb + sp) * 768 + db + q * 16];
        hf8 v0 = *(const hf8*)src;
        hf8 v1 = *(const hf8*)(src + 8);
        hf2x4 w0 = __builtin_bit_cast(hf2x4, v0);
        hf2x4 w1 = __builtin_bit_cast(hf2x4, v1);
#pragma unroll
        for (int e = 0; e < 4; ++e)
            pt[q * 8 + e][sp] = w0.v[e];
#pragma unroll
        for (int e = 0; e < 4; ++e)
            pt[q * 8 + 4 + e][sp] = w1.v[e];
    }
    __syncthreads();

    float acc[8][4];
#pragma unroll
    for (int i = 0; i < 8; ++i)
#pragma unroll
        for (int j = 0; j < 4; ++j) acc[i][j] = 0.f;

    const hf2 one2 = {(_Float16)1.0f, (_Float16)1.0f};
#pragma unroll 2
    for (int g = 0; g < 8; ++g) {
        hf2x4 F2[8];
#pragma unroll
        for (int i = 0; i < 8; ++i)
            F2[i] = __builtin_bit_cast(hf2x4,
                        *(const hf8*)&fs[tr + 16 * i][g * 8]);
        hf2x4 P2[4];
#pragma unroll
        for (int q = 0; q < 4; ++q)
            P2[q] = __builtin_bit_cast(hf2x4,
                        *(const hf8*)&pt[g * 4 + q][tp * 4]);
#pragma unroll
        for (int q = 0; q < 4; ++q) {
#pragma unroll
            for (int j = 0; j < 4; ++j) {
                const hf2 pj = P2[q].v[j];
#pragma unroll
                for (int i = 0; i < 8; ++i) {
                    hf2 d = F2[i].v[q] - pj;
                    unsigned ud = __builtin_bit_cast(unsigned, d) & 0x7FFF7FFFu;
                    acc[i][j] = FDOT2(__builtin_bit_cast(hf2, ud), one2, acc[i][j]);
                }
            }
        }
    }
    const int p = pb + tp * 4;
    if (p < 200) {
#pragma unroll
        for (int i = 0; i < 8; ++i) {
            float4 v = {-acc[i][0], -acc[i][1], -acc[i][2], -acc[i][3]};
            *(float4*)&part[((size_t)(rb + tr + 16 * i) * 12 + blockIdx.z) * 200 + p] = v;
        }
    }
}

// out[row][p] = sum_z part[row][z][p]; one block per row (9.6KB contiguous)
__global__ __launch_bounds__(256) void l1_reduce(
    const float* __restrict__ part, float* __restrict__ out)
{
    const int row = blockIdx.x;
    const int p = threadIdx.x;
    if (p < 200) {
        float s = 0.f;
#pragma unroll
        for (int z = 0; z < 12; ++z)
            s += part[((size_t)row * 12 + z) * 200 + p];
        out[(size_t)row * 200 + p] = s;
    }
}

// ---------------------------------------------------------------------------
// Workspace layout (bytes). Total ~23.2 MB.
// PART (19.66 MB) aliases the GEMM-era scratch (xb..adFH, dead when l1 runs).
// ---------------------------------------------------------------------------
static constexpr size_t OFF_PART  = 0;          // 2048 x 12 x 200 f32 partials
static constexpr size_t OFF_XB    = 0;          // 2048x768 bf16 (dead before l1)
static constexpr size_t OFF_AWB   = 3145728;    // 768x768 bf16
static constexpr size_t OFF_WD0   = 4325376;    // 384x768
static constexpr size_t OFF_WD1   = 4915200;    // 192x384
static constexpr size_t OFF_WD2   = 5062656;    // 128x192
static constexpr size_t OFF_WD3   = 5111808;    // 64x128
static constexpr size_t OFF_WU0   = 5128192;    // 128x64
static constexpr size_t OFF_WU1   = 5144576;    // 192x128
static constexpr size_t OFF_WU2   = 5193728;    // 384x192
static constexpr size_t OFF_WU3   = 5341184;    // 768x384
static constexpr size_t OFF_H1    = 5931008;    // 2048x384 bf16
static constexpr size_t OFF_U2    = 10387456;   // 2048x384 bf16
static constexpr size_t OFF_ADF   = 11960320;   // 2048x768 f16: x + adapter(x)
static constexpr size_t OFF_FEATH = 19660800;   // 2048x768 f16: features
static constexpr size_t OFF_PROH  = 22806528;   // 256x768 f16: protos (padded)

extern "C" void kernel_launch(void* const* d_in, const int* in_sizes, int n_in,
                              void* d_out, int out_size, void* d_ws, size_t ws_size,
                              hipStream_t stream) {
    const float* x      = (const float*)d_in[0];
    const float* aW     = (const float*)d_in[1];
    const float* ab     = (const float*)d_in[2];
    const float* protos = (const float*)d_in[3];
    const float* Wd[4]  = {(const float*)d_in[4], (const float*)d_in[6],
                           (const float*)d_in[8], (const float*)d_in[10]};
    const float* bd[4]  = {(const float*)d_in[5], (const float*)d_in[7],
                           (const float*)d_in[9], (const float*)d_in[11]};
    const float* Wu[4]  = {(const float*)d_in[12], (const float*)d_in[14],
                           (const float*)d_in[16], (const float*)d_in[18]};
    const float* bu[4]  = {(const float*)d_in[13], (const float*)d_in[15],
                           (const float*)d_in[17], (const float*)d_in[19]};
    float* out = (float*)d_out;
    char* ws = (char*)d_ws;

    u16* xb    = (u16*)(ws + OFF_XB);
    u16* aWb   = (u16*)(ws + OFF_AWB);
    u16* Wd0b  = (u16*)(ws + OFF_WD0);
    u16* Wd1b  = (u16*)(ws + OFF_WD1);
    u16* Wd2b  = (u16*)(ws + OFF_WD2);
    u16* Wd3b  = (u16*)(ws + OFF_WD3);
    u16* Wu0b  = (u16*)(ws + OFF_WU0);
    u16* Wu1b  = (u16*)(ws + OFF_WU1);
    u16* Wu2b  = (u16*)(ws + OFF_WU2);
    u16* Wu3b  = (u16*)(ws + OFF_WU3);
    u16* h1    = (u16*)(ws + OFF_H1);
    u16* u2    = (u16*)(ws + OFF_U2);
    float* part = (float*)(ws + OFF_PART);
    _Float16* adFH  = (_Float16*)(ws + OFF_ADF);
    _Float16* featH = (_Float16*)(ws + OFF_FEATH);
    _Float16* proH  = (_Float16*)(ws + OFF_PROH);

    // --- 1. convert/pad everything (bf16 for GEMM, f16 for L1) ---
    CvtTab tab;
    int blk = 0;
    auto set = [&](int i, const float* s, u16* d, int N, int K, int Np, int Kp,
                   int fmt) {
        tab.t[i] = {s, d, N, K, Np, Kp, blk, fmt};
        blk += (Np * Kp + 255) / 256;
    };
    set(0,  x,      xb,          2048, 768, 2048, 768, 0);
    set(1,  aW,     aWb,         768,  768, 768,  768, 0);
    set(2,  Wd[0],  Wd0b,        384,  768, 384,  768, 0);
    set(3,  Wd[1],  Wd1b,        192,  384, 192,  384, 0);
    set(4,  Wd[2],  Wd2b,        96,   192, 128,  192, 0);
    set(5,  Wd[3],  Wd3b,        48,   96,  64,   128, 0);
    set(6,  Wu[0],  Wu0b,        96,   48,  128,  64,  0);
    set(7,  Wu[1],  Wu1b,        192,  96,  192,  128, 0);
    set(8,  Wu[2],  Wu2b,        384,  192, 384,  192, 0);
    set(9,  Wu[3],  Wu3b,        768,  384, 768,  384, 0);
    set(10, protos, (u16*)proH,  200,  768, 256,  768, 1);
    cvt_all<<<blk, 256, 0, stream>>>(tab);

    // --- 2. adapter + down0 (2-phase 128x64 dbuf), chain, u3 ---
    gemm_ad0<<<dim3(16, 18), 256, 0, stream>>>(xb, aWb, ab, adFH, Wd0b, bd[0], h1);
    chain_mid<<<dim3(128), 256, 0, stream>>>(h1,
        Wd1b, bd[1], Wd2b, bd[2], Wd3b, bd[3],
        Wu0b, bu[0], Wu1b, bu[1], Wu2b, bu[2], u2);
    gemm_u3<<<dim3(16, 12), 256, 0, stream>>>(u2, Wu3b, bu[3], adFH, featH);

    // --- 3. L1 prototype head: partials (no atomics), then reduce ---
    l1_kernel<<<dim3(16, 4, 12), 256, 0, stream>>>(featH, proH, part);
    l1_reduce<<<dim3(2048), 256, 0, stream>>>(part, out);
}